// Round 18
// baseline (138.528 us; speedup 1.0000x reference)
//
#include <hip/hip_runtime.h>
#include <hip/hip_bf16.h>
#include <hip/hip_fp16.h>

#define B_DIM 8
#define N_DIM 1024
#define C_DIM 768
#define H_DIM 12
#define HD    64
#define M_DIM (B_DIM * N_DIM)   // 8192
#define BH    (B_DIM * H_DIM)   // 96

static constexpr size_t TEN = (size_t)M_DIM * C_DIM;     // 6,291,456
static constexpr size_t WN  = (size_t)C_DIM * C_DIM;     // 589,824

typedef __attribute__((ext_vector_type(8))) short    s16x8;
typedef __attribute__((ext_vector_type(8))) _Float16 f16x8;
typedef __attribute__((ext_vector_type(4))) float    f32x4;

__device__ __forceinline__ unsigned short f2h(float f) {
    __half h = __float2half(f);          // RTN
    return __half_as_ushort(h);
}

// pk layout: addr(m,k) = ((((m>>7)*24 + (k>>5))*4 + ((k>>3)&3))*128 + (m&127))*8 + (k&7)

// ---------------------------------------------------------------------------
// fp32 -> fp16 pk-layout convert: z=0..2 -> q/k/v (64 panels);
// z=3 -> the four weight matrices packed as p'=t*6+wp (24 panel-units).
// Block (24,64,4); block (0,0,3) also fills the 512-entry cos/sin table.
// ---------------------------------------------------------------------------
__global__ __launch_bounds__(256)
void convAll(const float* __restrict__ q, const float* __restrict__ k,
             const float* __restrict__ v,
             const float* __restrict__ wq, const float* __restrict__ wk,
             const float* __restrict__ wv, const float* __restrict__ wo,
             unsigned short* __restrict__ XS, unsigned short* __restrict__ WS,
             float2* __restrict__ tab)
{
    const int z  = blockIdx.z;
    const int p  = blockIdx.y;
    const int kb = blockIdx.x;

    if (z == 3 && p == 0 && kb == 0) {
        #pragma unroll
        for (int i = 0; i < 2; ++i) {
            int t = threadIdx.x + i * 256;       // 0..511
            int pos = t >> 4, j = t & 15;
            float ang = (float)pos * exp2f(-(float)j * 0.41524101186092029f);
            float s, c;
            sincosf(ang, &s, &c);
            tab[t] = make_float2(c, s);
        }
    }

    const float* src;
    unsigned short* dst;
    int panel;
    if (z < 3) {
        src = (z == 0) ? q : (z == 1 ? k : v);
        dst = XS + (size_t)z * TEN;
        panel = p;                               // 0..63
    } else {
        if (p >= 24) return;
        int t = p / 6;
        src = (t == 0) ? wq : (t == 1 ? wk : (t == 2 ? wv : wo));
        dst = WS + (size_t)t * WN;
        panel = p % 6;                           // 0..5
    }

    const int mr = threadIdx.x & 127;
    const int gh = threadIdx.x >> 7;             // 0/1
    const float* s = src + ((size_t)(panel * 128 + mr)) * C_DIM + kb * 32 + gh * 16;
    float4 v0 = *(const float4*)(s);
    float4 v1 = *(const float4*)(s + 4);
    float4 v2 = *(const float4*)(s + 8);
    float4 v3 = *(const float4*)(s + 12);
    float f[16] = {v0.x,v0.y,v0.z,v0.w, v1.x,v1.y,v1.z,v1.w,
                   v2.x,v2.y,v2.z,v2.w, v3.x,v3.y,v3.z,v3.w};
    #pragma unroll
    for (int gj = 0; gj < 2; ++gj) {
        int gg = gh * 2 + gj;
        s16x8 h8;
        #pragma unroll
        for (int e = 0; e < 8; ++e)
            h8[e] = (short)f2h(f[gj * 8 + e]);
        size_t a = ((((size_t)panel * 24 + kb) * 4 + gg) * 128 + mr) * 8;
        *(s16x8*)(dst + a) = h8;
    }
}

// ---------------------------------------------------------------------------
// fp16 single-pass MFMA GEMM, BK=32, 4 waves (2x2).
// MODE 1 (QKV): BM=128 BN=128, acc[4][4]; T3-minimal schedule: ONE barrier +
//   ONE vmcnt(0) per K-step -- stage(kb+1) issued at iteration top (safe: the
//   previous end-of-iter barrier guarantees buf^1's reads are done), its HBM
//   latency hides under the whole compute phase.
//   z=0/1 fused RoPE -> fp16 head layout (Q scaled 0.125*log2e);
//   z=2 -> V^T (B,H,64,N) via LDS transpose epilogue.
// MODE 0 (O-proj): BM=128 BN=64, acc[4][2], R12 two-barrier schedule (control).
// ---------------------------------------------------------------------------
template<int MODE>
__global__ __launch_bounds__(256)
void gemmF(const unsigned short* __restrict__ XQ, const unsigned short* __restrict__ XK,
           const unsigned short* __restrict__ XV,
           const unsigned short* __restrict__ WQ, const unsigned short* __restrict__ WK,
           const unsigned short* __restrict__ WV,
           const int* __restrict__ qpos, const int* __restrict__ kpos,
           const float2* __restrict__ tab,
           unsigned short* __restrict__ OQ, unsigned short* __restrict__ OK_,
           unsigned short* __restrict__ OV,
           const float* __restrict__ bias, float* __restrict__ Of)
{
    extern __shared__ unsigned short smem_us[];
    auto sA = reinterpret_cast<unsigned short (*)[4][128][8]>(smem_us);          // [2][4][128][8] 16KB

    const int tid  = threadIdx.x;
    const int lane = tid & 63;
    const int w    = tid >> 6;
    const int wr   = w >> 1, wc = w & 1;
    const int c    = lane & 15, g = lane >> 4;

    const int chunk = gridDim.x >> 3;
    const int wgid  = (blockIdx.x & 7) * chunk + (blockIdx.x >> 3);
    int z, m0, n0;
    if (MODE == 1) {
        z = wgid / 384;
        int r = wgid - z * 384;
        m0 = (r / 6) * 128;
        n0 = (r % 6) * 128;
    } else {
        z = 0;
        m0 = (wgid / 12) * 128;
        n0 = (wgid % 12) * 64;
    }

    const unsigned short *Ap, *Bp;
    if (MODE == 0 || z == 0) { Ap = XQ; Bp = WQ; }
    else if (z == 1)         { Ap = XK; Bp = WK; }
    else                     { Ap = XV; Bp = WV; }

    const size_t abase0 = (size_t)(m0 >> 7) * 24 * 4096;
    const size_t bbase0 = (size_t)(n0 >> 7) * 24 * 4096;

    if constexpr (MODE == 1) {
        auto sB = reinterpret_cast<unsigned short (*)[4][128][8]>(smem_us + 8192);   // 16KB

        f32x4 acc[4][4] = {};

        auto stage = [&](int kb, int buf) {
            #pragma unroll
            for (int t = 0; t < 4; ++t) {
                int is = w * 4 + t;                 // 0..15, wave-uniform
                int sel = is >> 3;                  // 0:A 1:B
                int j   = is & 7;
                int gg  = j >> 1, half = j & 1;
                const unsigned short* srcp =
                    (sel ? Bp + bbase0 : Ap + abase0) + (size_t)kb * 4096
                    + (size_t)gg * 1024 + (half * 64 + lane) * 8;
                unsigned short* dstp = sel ? &sB[buf][gg][half * 64][0]
                                           : &sA[buf][gg][half * 64][0];
                __builtin_amdgcn_global_load_lds(
                    (const __attribute__((address_space(1))) void*)srcp,
                    (__attribute__((address_space(3))) void*)dstp,
                    16, 0, 0);
            }
        };

        // prologue: buf0 staged and drained
        stage(0, 0);
        asm volatile("s_waitcnt vmcnt(0)" ::: "memory");
        __builtin_amdgcn_sched_barrier(0);
        __builtin_amdgcn_s_barrier();
        __builtin_amdgcn_sched_barrier(0);

        for (int kb = 0; kb < 24; ++kb) {
            int buf = kb & 1;
            // stage next tile NOW; latency hides under this iter's compute.
            // Safe: end-of-iter barrier of kb-1 finished all reads of buf^1.
            if (kb + 1 < 24) stage(kb + 1, buf ^ 1);

            f16x8 a[4], b[4];
            #pragma unroll
            for (int mi = 0; mi < 4; ++mi)
                a[mi] = *(const f16x8*)&sA[buf][g][wr * 64 + 16 * mi + c][0];
            #pragma unroll
            for (int ni = 0; ni < 4; ++ni)
                b[ni] = *(const f16x8*)&sB[buf][g][wc * 64 + 16 * ni + c][0];
            __builtin_amdgcn_s_setprio(1);
            #pragma unroll
            for (int mi = 0; mi < 4; ++mi)
                #pragma unroll
                for (int ni = 0; ni < 4; ++ni)
                    acc[mi][ni] = __builtin_amdgcn_mfma_f32_16x16x32_f16(a[mi], b[ni], acc[mi][ni], 0, 0, 0);
            __builtin_amdgcn_s_setprio(0);

            // staged tile landed + all reads of buf done -> next iter may flip
            asm volatile("s_waitcnt vmcnt(0)" ::: "memory");
            __builtin_amdgcn_sched_barrier(0);
            __builtin_amdgcn_s_barrier();
            __builtin_amdgcn_sched_barrier(0);
        }

        if (z == 2) {
            // V tile -> LDS transpose (reuse staging LDS) -> V^T (B,H,64,N)
            __syncthreads();
            auto T = reinterpret_cast<unsigned short (*)[132]>(smem_us);   // [128][132] 33KB
            #pragma unroll
            for (int ni = 0; ni < 4; ++ni) {
                int dl = wc * 64 + 16 * ni + c;
                #pragma unroll
                for (int mi = 0; mi < 4; ++mi) {
                    int ml = wr * 64 + 16 * mi + 4 * g;
                    unsigned short hs[4];
                    #pragma unroll
                    for (int r = 0; r < 4; ++r)
                        hs[r] = f2h(acc[mi][ni][r]);
                    *(uint2*)&T[dl][ml] =
                        make_uint2((unsigned)hs[0] | ((unsigned)hs[1] << 16),
                                   (unsigned)hs[2] | ((unsigned)hs[3] << 16));
                }
            }
            __syncthreads();
            const int b = m0 >> 10, nbase = m0 & 1023;
            #pragma unroll
            for (int it = 0; it < 8; ++it) {
                int f  = tid + it * 256;         // 0..2047
                int dl = f >> 4;                 // 0..127
                int mc = (f & 15) * 8;           // 0..120
                s16x8 vv = *(const s16x8*)&T[dl][mc];
                int d = n0 + dl, h = d >> 6, dh = d & 63;
                *(s16x8*)(OV + ((size_t)(b * H_DIM + h) * HD + dh) * N_DIM + nbase + mc) = vv;
            }
        } else {
            // Q/K: fused RoPE -> fp16 head layout; Q folds log2e for exp2 softmax
            const int* P = z ? kpos : qpos;
            unsigned short* T = z ? OK_ : OQ;
            const float scale = z ? 1.0f : 0.18033688011112042f;   // 0.125 * log2e
            const int hh = (n0 >> 6) + wc;
            #pragma unroll
            for (int mi = 0; mi < 4; ++mi)
                #pragma unroll
                for (int r = 0; r < 4; ++r) {
                    int m = m0 + wr * 64 + 16 * mi + 4 * g + r;
                    int b = m >> 10, n = m & 1023;
                    size_t base = ((size_t)(b * H_DIM + hh) * N_DIM + n) * HD;
                    #pragma unroll
                    for (int bb = 0; bb < 2; ++bb) {
                        int pos = P[2 * m + bb];
                        float2 cs = tab[pos * 16 + c];
                        float x1 = acc[mi][bb * 2 + 0][r];
                        float x2 = acc[mi][bb * 2 + 1][r];
                        float r1 = (x1 * cs.x - x2 * cs.y) * scale;
                        float r2 = (x2 * cs.x + x1 * cs.y) * scale;
                        T[base + bb * 32 + c]      = f2h(r1);
                        T[base + bb * 32 + 16 + c] = f2h(r2);
                    }
                }
        }
    } else {
        // ---- MODE 0: BN=64 (768 blocks, 3/CU), R12 two-barrier schedule ----
        auto sB = reinterpret_cast<unsigned short (*)[4][64][8]>(smem_us + 8192);    // 8KB
        const int r0 = n0 & 127;              // 0 or 64: row base inside B panel

        f32x4 acc[4][2] = {};

        auto stage = [&](int kb, int buf) {
            #pragma unroll
            for (int t = 0; t < 3; ++t) {
                int is = w * 3 + t;                 // 0..11, wave-uniform
                if (is < 8) {                       // A: 8 slabs
                    int gg = is & 3, half = is >> 2;
                    const unsigned short* srcp = Ap + abase0 + (size_t)kb * 4096
                        + (size_t)gg * 1024 + (half * 64 + lane) * 8;
                    __builtin_amdgcn_global_load_lds(
                        (const __attribute__((address_space(1))) void*)srcp,
                        (__attribute__((address_space(3))) void*)&sA[buf][gg][half * 64][0],
                        16, 0, 0);
                } else {                            // B: 4 slabs (64 rows)
                    int gg = is - 8;
                    const unsigned short* srcp = Bp + bbase0 + (size_t)kb * 4096
                        + (size_t)gg * 1024 + (r0 + lane) * 8;
                    __builtin_amdgcn_global_load_lds(
                        (const __attribute__((address_space(1))) void*)srcp,
                        (__attribute__((address_space(3))) void*)&sB[buf][gg][0][0],
                        16, 0, 0);
                }
            }
        };

        stage(0, 0);
        stage(1, 1);

        for (int kb = 0; kb < 24; ++kb) {
            int buf = kb & 1;
            if (kb < 23) asm volatile("s_waitcnt vmcnt(3)" ::: "memory");
            else         asm volatile("s_waitcnt vmcnt(0)" ::: "memory");
            __builtin_amdgcn_sched_barrier(0);
            __builtin_amdgcn_s_barrier();
            __builtin_amdgcn_sched_barrier(0);

            f16x8 a[4], b[2];
            #pragma unroll
            for (int mi = 0; mi < 4; ++mi)
                a[mi] = *(const f16x8*)&sA[buf][g][wr * 64 + 16 * mi + c][0];
            #pragma unroll
            for (int ni = 0; ni < 2; ++ni)
                b[ni] = *(const f16x8*)&sB[buf][g][wc * 32 + 16 * ni + c][0];
            __builtin_amdgcn_s_setprio(1);
            #pragma unroll
            for (int mi = 0; mi < 4; ++mi)
                #pragma unroll
                for (int ni = 0; ni < 2; ++ni)
                    acc[mi][ni] = __builtin_amdgcn_mfma_f32_16x16x32_f16(a[mi], b[ni], acc[mi][ni], 0, 0, 0);
            __builtin_amdgcn_s_setprio(0);

            __builtin_amdgcn_sched_barrier(0);
            __builtin_amdgcn_s_barrier();
            __builtin_amdgcn_sched_barrier(0);
            if (kb + 2 < 24) stage(kb + 2, buf);
        }

        #pragma unroll
        for (int ni = 0; ni < 2; ++ni) {
            int d = n0 + wc * 32 + 16 * ni + c;
            float bv = bias[d];
            #pragma unroll
            for (int mi = 0; mi < 4; ++mi)
                #pragma unroll
                for (int r = 0; r < 4; ++r) {
                    int m = m0 + wr * 64 + 16 * mi + 4 * g + r;
                    Of[(size_t)m * C_DIM + d] = acc[mi][ni][r] + bv;
                }
        }
    }
}

// ---------------------------------------------------------------------------
// fp16 MFMA flash attention, QBLK=128, XCD-pinned, no-max exp2 softmax,
// MFMA denominator, T14 reg-prefetch across barriers (R12 config, best).
// ---------------------------------------------------------------------------
__global__ __launch_bounds__(256)
void attn_f16(const unsigned short* __restrict__ Qh, const unsigned short* __restrict__ Kh,
              const unsigned short* __restrict__ Vt,
              unsigned short* __restrict__ Xb)
{
    __shared__ _Float16 sK[64][72];
    __shared__ _Float16 sV[64][72];
    __shared__ _Float16 sP[4][2][16][72];

    const int tid  = threadIdx.x;
    const int lane = tid & 63;
    const int wv   = tid >> 6;
    const int c    = lane & 15;
    const int g    = lane >> 4;

    const int bid   = blockIdx.x;
    const int xcd   = bid & 7;               // HW round-robins blocks to XCDs
    const int local = bid >> 3;              // 0..95
    const int bh    = xcd * 12 + (local >> 3);
    const int q0    = (local & 7) * 128;
    const size_t hb = (size_t)bh * (N_DIM * HD);

    const size_t qoffA = hb + (size_t)(q0 + wv * 32 + c) * HD;
    const size_t qoffB = qoffA + (size_t)16 * HD;
    f16x8 qA0 = *(const f16x8*)(Qh + qoffA + 8 * g);
    f16x8 qA1 = *(const f16x8*)(Qh + qoffA + 32 + 8 * g);
    f16x8 qB0 = *(const f16x8*)(Qh + qoffB + 8 * g);
    f16x8 qB1 = *(const f16x8*)(Qh + qoffB + 32 + 8 * g);

    f16x8 ones;
    #pragma unroll
    for (int e = 0; e < 8; ++e) ones[e] = (_Float16)1.0f;

    f32x4 accA[4] = {}, accB[4] = {};
    f32x4 lAcc[2] = {};

    const int f0 = tid, f1 = tid + 256;
    const int row0 = f0 >> 3, ch0 = (f0 & 7) * 8;
    const int row1 = f1 >> 3, ch1 = (f1 & 7) * 8;
    const unsigned short* Kbase = Kh + hb;
    const unsigned short* Vbase = Vt + hb;

    s16x8 rK0 = *(const s16x8*)(Kbase + (size_t)row0 * HD + ch0);
    s16x8 rK1 = *(const s16x8*)(Kbase + (size_t)row1 * HD + ch1);
    s16x8 rV0 = *(const s16x8*)(Vbase + (size_t)row0 * N_DIM + ch0);
    s16x8 rV1 = *(const s16x8*)(Vbase + (size_t)row1 * N_DIM + ch1);

    for (int kt = 0; kt < 16; ++kt) {
        __builtin_amdgcn_s_barrier();

        *(s16x8*)&sK[row0][ch0] = rK0;
        *(s16x8*)&sK[row1][ch1] = rK1;
        *(s16x8*)&sV[row0][ch0] = rV0;
        *(s16x8*)&sV[row1][ch1] = rV1;

        if (kt < 15) {
            rK0 = *(const s16x8*)(Kbase + (size_t)((kt + 1) * 64 + row0) * HD + ch0);
            rK1 = *(const s16x8*)(Kbase + (size_t)((kt + 1) * 64 + row1) * HD + ch1);
            rV0 = *(const s16x8*)(Vbase + (size_t)row0 * N_DIM + (kt + 1) * 64 + ch0);
            rV1 = *(const s16x8*)(Vbase + (size_t)row1 * N_DIM + (kt + 1) * 64 + ch1);
        }

        asm volatile("s_waitcnt lgkmcnt(0)" ::: "memory");
        __builtin_amdgcn_sched_barrier(0);
        __builtin_amdgcn_s_barrier();
        __builtin_amdgcn_sched_barrier(0);

        f32x4 sA[4] = {}, sB[4] = {};
        __builtin_amdgcn_s_setprio(1);
        #pragma unroll
        for (int st = 0; st < 4; ++st) {
            f16x8 a0 = *(const f16x8*)&sK[16 * st + c][8 * g];
            f16x8 a1 = *(const f16x8*)&sK[16 * st + c][32 + 8 * g];
            sA[st] = __builtin_amdgcn_mfma_f32_16x16x32_f16(a0, qA0, sA[st], 0, 0, 0);
            sA[st] = __builtin_amdgcn_mfma_f32_16x16x32_f16(a1, qA1, sA[st], 0, 0, 0);
            sB[st] = __builtin_amdgcn_mfma_f32_16x16x32_f16(a0, qB0, sB[st], 0, 0, 0);
            sB[st] = __builtin_amdgcn_mfma_f32_16x16x32_f16(a1, qB1, sB[st], 0, 0, 0);
        }
        __builtin_amdgcn_s_setprio(0);

        #pragma unroll
        for (int st = 0; st < 4; ++st) {
            float pA[4], pB[4];
            #pragma unroll
            for (int r = 0; r < 4; ++r) {
                pA[r] = __builtin_amdgcn_exp2f(sA[st][r]);
                pB[r] = __builtin_amdgcn_exp2f(sB[st][r]);
            }
            __half2 a01 = __float22half2_rn(make_float2(pA[0], pA[1]));
            __half2 a23 = __float22half2_rn(make_float2(pA[2], pA[3]));
            __half2 b01 = __float22half2_rn(make_float2(pB[0], pB[1]));
            __half2 b23 = __float22half2_rn(make_float2(pB[2], pB[3]));
            *(uint2*)&sP[wv][0][c][16 * st + 4 * g] =
                make_uint2(*(unsigned*)&a01, *(unsigned*)&a23);
            *(uint2*)&sP[wv][1][c][16 * st + 4 * g] =
                make_uint2(*(unsigned*)&b01, *(unsigned*)&b23);
        }

        __builtin_amdgcn_s_setprio(1);
        #pragma unroll
        for (int m = 0; m < 2; ++m) {
            f16x8 pbA = *(const f16x8*)&sP[wv][0][c][32 * m + 8 * g];
            f16x8 pbB = *(const f16x8*)&sP[wv][1][c][32 * m + 8 * g];
            #pragma unroll
            for (int sd = 0; sd < 4; ++sd) {
                f16x8 va = *(const f16x8*)&sV[16 * sd + c][32 * m + 8 * g];
                accA[sd] = __builtin_amdgcn_mfma_f32_16x16x32_f16(va, pbA, accA[sd], 0, 0, 0);
                accB[sd] = __builtin_amdgcn_mfma_f32_16x16x32_f16(va, pbB, accB[sd], 0, 0, 0);
            }
            lAcc[0] = __builtin_amdgcn_mfma_f32_16x16x32_f16(ones, pbA, lAcc[0], 0, 0, 0);
            lAcc[1] = __builtin_amdgcn_mfma_f32_16x16x32_f16(ones, pbB, lAcc[1], 0, 0, 0);
        }
        __builtin_amdgcn_s_setprio(0);
    }

    float invA = 1.0f / lAcc[0][0];
    float invB = 1.0f / lAcc[1][0];

    const int b = bh / H_DIM, h = bh % H_DIM;
    #pragma unroll
    for (int sub = 0; sub < 2; ++sub) {
        const f32x4* acc = sub ? accB : accA;
        float invl = sub ? invB : invA;
        const int q = q0 + wv * 32 + sub * 16 + c;
        const int m  = b * N_DIM + q;
        const int p_ = m >> 7, mr = m & 127;
        #pragma unroll
        for (int sd = 0; sd < 4; ++sd) {
            int kdim = h * 64 + 16 * sd + 4 * g;
            int kb = kdim >> 5;
            int gg = (kdim >> 3) & 3;
            int e  = kdim & 7;               // 0 or 4
            size_t a = ((((size_t)p_ * 24 + kb) * 4 + gg) * 128 + mr) * 8 + e;
            unsigned short hs[4];
            #pragma unroll
            for (int r = 0; r < 4; ++r)
                hs[r] = f2h(acc[sd][r] * invl);
            *(uint2*)(Xb + a) =
                make_uint2((unsigned)hs[0] | ((unsigned)hs[1] << 16),
                           (unsigned)hs[2] | ((unsigned)hs[3] << 16));
        }
    }
}

// ---------------------------------------------------------------------------
extern "C" void kernel_launch(void* const* d_in, const int* in_sizes, int n_in,
                              void* d_out, int out_size, void* d_ws, size_t ws_size,
                              hipStream_t stream)
{
    const float* query = (const float*)d_in[0];
    const float* key_  = (const float*)d_in[1];
    const float* value = (const float*)d_in[2];
    const int*   qpos  = (const int*)d_in[3];
    const int*   kpos  = (const int*)d_in[4];
    const float* Wq    = (const float*)d_in[5];
    const float* Wk    = (const float*)d_in[6];
    const float* Wv    = (const float*)d_in[7];
    const float* Wo    = (const float*)d_in[8];
    const float* bo    = (const float*)d_in[9];
    float* out = (float*)d_out;

    unsigned short* XS  = (unsigned short*)d_ws;     // 3 x TEN (pk fp16 q,k,v)
    unsigned short* WS  = XS + 3 * TEN;              // 4 x WN  (pk fp16 Wq..Wo)
    unsigned short* Qh  = WS + 4 * WN;               // fp16 head layout
    unsigned short* Kh  = Qh + TEN;
    unsigned short* Vt  = Kh + TEN;                  // fp16 (B,H,64,N)
    unsigned short* Xb  = Vt + TEN;                  // fp16 (pk)
    float2* tab = (float2*)(Xb + TEN);               // 512 float2

    convAll<<<dim3(24, 64, 4), 256, 0, stream>>>(
        query, key_, value, Wq, Wk, Wv, Wo, XS, WS, tab);

    gemmF<1><<<dim3(1152), 256, 33792, stream>>>(
        XS + 0 * TEN, XS + 1 * TEN, XS + 2 * TEN,
        WS + 0 * WN, WS + 1 * WN, WS + 2 * WN,
        qpos, kpos, tab, Qh, Kh, Vt, nullptr, nullptr);

    attn_f16<<<dim3(768), 256, 0, stream>>>(Qh, Kh, Vt, Xb);

    gemmF<0><<<dim3(768), 256, 24576, stream>>>(
        Xb, nullptr, nullptr,
        WS + 3 * WN, nullptr, nullptr,
        nullptr, nullptr, nullptr, nullptr, nullptr, nullptr, bo, out);
}

// Round 19
// 129.231 us; speedup vs baseline: 1.0719x; 1.0719x over previous
//
#include <hip/hip_runtime.h>
#include <hip/hip_bf16.h>
#include <hip/hip_fp16.h>

#define B_DIM 8
#define N_DIM 1024
#define C_DIM 768
#define H_DIM 12
#define HD    64
#define M_DIM (B_DIM * N_DIM)   // 8192
#define BH    (B_DIM * H_DIM)   // 96

static constexpr size_t TEN = (size_t)M_DIM * C_DIM;     // 6,291,456
static constexpr size_t WN  = (size_t)C_DIM * C_DIM;     // 589,824

typedef __attribute__((ext_vector_type(8))) short    s16x8;
typedef __attribute__((ext_vector_type(8))) _Float16 f16x8;
typedef __attribute__((ext_vector_type(4))) float    f32x4;

__device__ __forceinline__ unsigned short f2h(float f) {
    __half h = __float2half(f);          // RTN
    return __half_as_ushort(h);
}

// pk layout: addr(m,k) = ((((m>>7)*24 + (k>>5))*4 + ((k>>3)&3))*128 + (m&127))*8 + (k&7)

// ---------------------------------------------------------------------------
// fp32 -> fp16 pk-layout convert: z=0..2 -> q/k/v (64 panels);
// z=3 -> the four weight matrices packed as p'=t*6+wp (24 panel-units).
// Block (24,64,4); block (0,0,3) also fills the 512-entry cos/sin table.
// ---------------------------------------------------------------------------
__global__ __launch_bounds__(256)
void convAll(const float* __restrict__ q, const float* __restrict__ k,
             const float* __restrict__ v,
             const float* __restrict__ wq, const float* __restrict__ wk,
             const float* __restrict__ wv, const float* __restrict__ wo,
             unsigned short* __restrict__ XS, unsigned short* __restrict__ WS,
             float2* __restrict__ tab)
{
    const int z  = blockIdx.z;
    const int p  = blockIdx.y;
    const int kb = blockIdx.x;

    if (z == 3 && p == 0 && kb == 0) {
        #pragma unroll
        for (int i = 0; i < 2; ++i) {
            int t = threadIdx.x + i * 256;       // 0..511
            int pos = t >> 4, j = t & 15;
            float ang = (float)pos * exp2f(-(float)j * 0.41524101186092029f);
            float s, c;
            sincosf(ang, &s, &c);
            tab[t] = make_float2(c, s);
        }
    }

    const float* src;
    unsigned short* dst;
    int panel;
    if (z < 3) {
        src = (z == 0) ? q : (z == 1 ? k : v);
        dst = XS + (size_t)z * TEN;
        panel = p;                               // 0..63
    } else {
        if (p >= 24) return;
        int t = p / 6;
        src = (t == 0) ? wq : (t == 1 ? wk : (t == 2 ? wv : wo));
        dst = WS + (size_t)t * WN;
        panel = p % 6;                           // 0..5
    }

    const int mr = threadIdx.x & 127;
    const int gh = threadIdx.x >> 7;             // 0/1
    const float* s = src + ((size_t)(panel * 128 + mr)) * C_DIM + kb * 32 + gh * 16;
    float4 v0 = *(const float4*)(s);
    float4 v1 = *(const float4*)(s + 4);
    float4 v2 = *(const float4*)(s + 8);
    float4 v3 = *(const float4*)(s + 12);
    float f[16] = {v0.x,v0.y,v0.z,v0.w, v1.x,v1.y,v1.z,v1.w,
                   v2.x,v2.y,v2.z,v2.w, v3.x,v3.y,v3.z,v3.w};
    #pragma unroll
    for (int gj = 0; gj < 2; ++gj) {
        int gg = gh * 2 + gj;
        s16x8 h8;
        #pragma unroll
        for (int e = 0; e < 8; ++e)
            h8[e] = (short)f2h(f[gj * 8 + e]);
        size_t a = ((((size_t)panel * 24 + kb) * 4 + gg) * 128 + mr) * 8;
        *(s16x8*)(dst + a) = h8;
    }
}

// ---------------------------------------------------------------------------
// fp16 single-pass MFMA GEMM, BK=32, 4 waves (2x2), R12 schedule (proven best
// in 4 A/B rounds): 2-buf, counted vmcnt, stage(kb+2) after the tail barrier
// -> two full compute phases of prefetch slack.
// MODE 1 (QKV): BM=128 BN=128, acc[4][4];
//   z=0/1 fused RoPE -> fp16 head layout (Q scaled 0.125*log2e);
//   z=2 -> V^T (B,H,64,N) via LDS transpose epilogue.
// MODE 0 (O-proj): BM=128 BN=64, acc[4][2] -> 768 blocks (3/CU); fp32 + bias.
// ---------------------------------------------------------------------------
template<int MODE>
__global__ __launch_bounds__(256)
void gemmF(const unsigned short* __restrict__ XQ, const unsigned short* __restrict__ XK,
           const unsigned short* __restrict__ XV,
           const unsigned short* __restrict__ WQ, const unsigned short* __restrict__ WK,
           const unsigned short* __restrict__ WV,
           const int* __restrict__ qpos, const int* __restrict__ kpos,
           const float2* __restrict__ tab,
           unsigned short* __restrict__ OQ, unsigned short* __restrict__ OK_,
           unsigned short* __restrict__ OV,
           const float* __restrict__ bias, float* __restrict__ Of)
{
    extern __shared__ unsigned short smem_us[];
    auto sA = reinterpret_cast<unsigned short (*)[4][128][8]>(smem_us);          // [2][4][128][8] 16KB

    const int tid  = threadIdx.x;
    const int lane = tid & 63;
    const int w    = tid >> 6;
    const int wr   = w >> 1, wc = w & 1;
    const int c    = lane & 15, g = lane >> 4;

    const int chunk = gridDim.x >> 3;
    const int wgid  = (blockIdx.x & 7) * chunk + (blockIdx.x >> 3);
    int z, m0, n0;
    if (MODE == 1) {
        z = wgid / 384;
        int r = wgid - z * 384;
        m0 = (r / 6) * 128;
        n0 = (r % 6) * 128;
    } else {
        z = 0;
        m0 = (wgid / 12) * 128;
        n0 = (wgid % 12) * 64;
    }

    const unsigned short *Ap, *Bp;
    if (MODE == 0 || z == 0) { Ap = XQ; Bp = WQ; }
    else if (z == 1)         { Ap = XK; Bp = WK; }
    else                     { Ap = XV; Bp = WV; }

    const size_t abase0 = (size_t)(m0 >> 7) * 24 * 4096;
    const size_t bbase0 = (size_t)(n0 >> 7) * 24 * 4096;

    if constexpr (MODE == 1) {
        auto sB = reinterpret_cast<unsigned short (*)[4][128][8]>(smem_us + 8192);   // 16KB

        f32x4 acc[4][4] = {};

        auto stage = [&](int kb, int buf) {
            #pragma unroll
            for (int t = 0; t < 4; ++t) {
                int is = w * 4 + t;                 // 0..15, wave-uniform
                int sel = is >> 3;                  // 0:A 1:B
                int j   = is & 7;
                int gg  = j >> 1, half = j & 1;
                const unsigned short* srcp =
                    (sel ? Bp + bbase0 : Ap + abase0) + (size_t)kb * 4096
                    + (size_t)gg * 1024 + (half * 64 + lane) * 8;
                unsigned short* dstp = sel ? &sB[buf][gg][half * 64][0]
                                           : &sA[buf][gg][half * 64][0];
                __builtin_amdgcn_global_load_lds(
                    (const __attribute__((address_space(1))) void*)srcp,
                    (__attribute__((address_space(3))) void*)dstp,
                    16, 0, 0);
            }
        };

        stage(0, 0);
        stage(1, 1);

        for (int kb = 0; kb < 24; ++kb) {
            int buf = kb & 1;
            if (kb < 23) asm volatile("s_waitcnt vmcnt(4)" ::: "memory");
            else         asm volatile("s_waitcnt vmcnt(0)" ::: "memory");
            __builtin_amdgcn_sched_barrier(0);
            __builtin_amdgcn_s_barrier();
            __builtin_amdgcn_sched_barrier(0);

            f16x8 a[4], b[4];
            #pragma unroll
            for (int mi = 0; mi < 4; ++mi)
                a[mi] = *(const f16x8*)&sA[buf][g][wr * 64 + 16 * mi + c][0];
            #pragma unroll
            for (int ni = 0; ni < 4; ++ni)
                b[ni] = *(const f16x8*)&sB[buf][g][wc * 64 + 16 * ni + c][0];
            __builtin_amdgcn_s_setprio(1);
            #pragma unroll
            for (int mi = 0; mi < 4; ++mi)
                #pragma unroll
                for (int ni = 0; ni < 4; ++ni)
                    acc[mi][ni] = __builtin_amdgcn_mfma_f32_16x16x32_f16(a[mi], b[ni], acc[mi][ni], 0, 0, 0);
            __builtin_amdgcn_s_setprio(0);

            __builtin_amdgcn_sched_barrier(0);
            __builtin_amdgcn_s_barrier();
            __builtin_amdgcn_sched_barrier(0);
            if (kb + 2 < 24) stage(kb + 2, buf);
        }

        if (z == 2) {
            // V tile -> LDS transpose (reuse staging LDS) -> V^T (B,H,64,N)
            __syncthreads();
            auto T = reinterpret_cast<unsigned short (*)[132]>(smem_us);   // [128][132] 33KB
            #pragma unroll
            for (int ni = 0; ni < 4; ++ni) {
                int dl = wc * 64 + 16 * ni + c;
                #pragma unroll
                for (int mi = 0; mi < 4; ++mi) {
                    int ml = wr * 64 + 16 * mi + 4 * g;
                    unsigned short hs[4];
                    #pragma unroll
                    for (int r = 0; r < 4; ++r)
                        hs[r] = f2h(acc[mi][ni][r]);
                    *(uint2*)&T[dl][ml] =
                        make_uint2((unsigned)hs[0] | ((unsigned)hs[1] << 16),
                                   (unsigned)hs[2] | ((unsigned)hs[3] << 16));
                }
            }
            __syncthreads();
            const int b = m0 >> 10, nbase = m0 & 1023;
            #pragma unroll
            for (int it = 0; it < 8; ++it) {
                int f  = tid + it * 256;         // 0..2047
                int dl = f >> 4;                 // 0..127
                int mc = (f & 15) * 8;           // 0..120
                s16x8 vv = *(const s16x8*)&T[dl][mc];
                int d = n0 + dl, h = d >> 6, dh = d & 63;
                *(s16x8*)(OV + ((size_t)(b * H_DIM + h) * HD + dh) * N_DIM + nbase + mc) = vv;
            }
        } else {
            // Q/K: fused RoPE -> fp16 head layout; Q folds log2e for exp2 softmax
            const int* P = z ? kpos : qpos;
            unsigned short* T = z ? OK_ : OQ;
            const float scale = z ? 1.0f : 0.18033688011112042f;   // 0.125 * log2e
            const int hh = (n0 >> 6) + wc;
            #pragma unroll
            for (int mi = 0; mi < 4; ++mi)
                #pragma unroll
                for (int r = 0; r < 4; ++r) {
                    int m = m0 + wr * 64 + 16 * mi + 4 * g + r;
                    int b = m >> 10, n = m & 1023;
                    size_t base = ((size_t)(b * H_DIM + hh) * N_DIM + n) * HD;
                    #pragma unroll
                    for (int bb = 0; bb < 2; ++bb) {
                        int pos = P[2 * m + bb];
                        float2 cs = tab[pos * 16 + c];
                        float x1 = acc[mi][bb * 2 + 0][r];
                        float x2 = acc[mi][bb * 2 + 1][r];
                        float r1 = (x1 * cs.x - x2 * cs.y) * scale;
                        float r2 = (x2 * cs.x + x1 * cs.y) * scale;
                        T[base + bb * 32 + c]      = f2h(r1);
                        T[base + bb * 32 + 16 + c] = f2h(r2);
                    }
                }
        }
    } else {
        // ---- MODE 0: BN=64 (768 blocks, 3/CU), R12 two-barrier schedule ----
        auto sB = reinterpret_cast<unsigned short (*)[4][64][8]>(smem_us + 8192);    // 8KB
        const int r0 = n0 & 127;              // 0 or 64: row base inside B panel

        f32x4 acc[4][2] = {};

        auto stage = [&](int kb, int buf) {
            #pragma unroll
            for (int t = 0; t < 3; ++t) {
                int is = w * 3 + t;                 // 0..11, wave-uniform
                if (is < 8) {                       // A: 8 slabs
                    int gg = is & 3, half = is >> 2;
                    const unsigned short* srcp = Ap + abase0 + (size_t)kb * 4096
                        + (size_t)gg * 1024 + (half * 64 + lane) * 8;
                    __builtin_amdgcn_global_load_lds(
                        (const __attribute__((address_space(1))) void*)srcp,
                        (__attribute__((address_space(3))) void*)&sA[buf][gg][half * 64][0],
                        16, 0, 0);
                } else {                            // B: 4 slabs (64 rows)
                    int gg = is - 8;
                    const unsigned short* srcp = Bp + bbase0 + (size_t)kb * 4096
                        + (size_t)gg * 1024 + (r0 + lane) * 8;
                    __builtin_amdgcn_global_load_lds(
                        (const __attribute__((address_space(1))) void*)srcp,
                        (__attribute__((address_space(3))) void*)&sB[buf][gg][0][0],
                        16, 0, 0);
                }
            }
        };

        stage(0, 0);
        stage(1, 1);

        for (int kb = 0; kb < 24; ++kb) {
            int buf = kb & 1;
            if (kb < 23) asm volatile("s_waitcnt vmcnt(3)" ::: "memory");
            else         asm volatile("s_waitcnt vmcnt(0)" ::: "memory");
            __builtin_amdgcn_sched_barrier(0);
            __builtin_amdgcn_s_barrier();
            __builtin_amdgcn_sched_barrier(0);

            f16x8 a[4], b[2];
            #pragma unroll
            for (int mi = 0; mi < 4; ++mi)
                a[mi] = *(const f16x8*)&sA[buf][g][wr * 64 + 16 * mi + c][0];
            #pragma unroll
            for (int ni = 0; ni < 2; ++ni)
                b[ni] = *(const f16x8*)&sB[buf][g][wc * 32 + 16 * ni + c][0];
            __builtin_amdgcn_s_setprio(1);
            #pragma unroll
            for (int mi = 0; mi < 4; ++mi)
                #pragma unroll
                for (int ni = 0; ni < 2; ++ni)
                    acc[mi][ni] = __builtin_amdgcn_mfma_f32_16x16x32_f16(a[mi], b[ni], acc[mi][ni], 0, 0, 0);
            __builtin_amdgcn_s_setprio(0);

            __builtin_amdgcn_sched_barrier(0);
            __builtin_amdgcn_s_barrier();
            __builtin_amdgcn_sched_barrier(0);
            if (kb + 2 < 24) stage(kb + 2, buf);
        }

        #pragma unroll
        for (int ni = 0; ni < 2; ++ni) {
            int d = n0 + wc * 32 + 16 * ni + c;
            float bv = bias[d];
            #pragma unroll
            for (int mi = 0; mi < 4; ++mi)
                #pragma unroll
                for (int r = 0; r < 4; ++r) {
                    int m = m0 + wr * 64 + 16 * mi + 4 * g + r;
                    Of[(size_t)m * C_DIM + d] = acc[mi][ni][r] + bv;
                }
        }
    }
}

// ---------------------------------------------------------------------------
// fp16 MFMA flash attention, QBLK=128, XCD-pinned, no-max exp2 softmax,
// MFMA denominator, T14 reg-prefetch across barriers (R12 config, best).
// ---------------------------------------------------------------------------
__global__ __launch_bounds__(256)
void attn_f16(const unsigned short* __restrict__ Qh, const unsigned short* __restrict__ Kh,
              const unsigned short* __restrict__ Vt,
              unsigned short* __restrict__ Xb)
{
    __shared__ _Float16 sK[64][72];
    __shared__ _Float16 sV[64][72];
    __shared__ _Float16 sP[4][2][16][72];

    const int tid  = threadIdx.x;
    const int lane = tid & 63;
    const int wv   = tid >> 6;
    const int c    = lane & 15;
    const int g    = lane >> 4;

    const int bid   = blockIdx.x;
    const int xcd   = bid & 7;               // HW round-robins blocks to XCDs
    const int local = bid >> 3;              // 0..95
    const int bh    = xcd * 12 + (local >> 3);
    const int q0    = (local & 7) * 128;
    const size_t hb = (size_t)bh * (N_DIM * HD);

    const size_t qoffA = hb + (size_t)(q0 + wv * 32 + c) * HD;
    const size_t qoffB = qoffA + (size_t)16 * HD;
    f16x8 qA0 = *(const f16x8*)(Qh + qoffA + 8 * g);
    f16x8 qA1 = *(const f16x8*)(Qh + qoffA + 32 + 8 * g);
    f16x8 qB0 = *(const f16x8*)(Qh + qoffB + 8 * g);
    f16x8 qB1 = *(const f16x8*)(Qh + qoffB + 32 + 8 * g);

    f16x8 ones;
    #pragma unroll
    for (int e = 0; e < 8; ++e) ones[e] = (_Float16)1.0f;

    f32x4 accA[4] = {}, accB[4] = {};
    f32x4 lAcc[2] = {};

    const int f0 = tid, f1 = tid + 256;
    const int row0 = f0 >> 3, ch0 = (f0 & 7) * 8;
    const int row1 = f1 >> 3, ch1 = (f1 & 7) * 8;
    const unsigned short* Kbase = Kh + hb;
    const unsigned short* Vbase = Vt + hb;

    s16x8 rK0 = *(const s16x8*)(Kbase + (size_t)row0 * HD + ch0);
    s16x8 rK1 = *(const s16x8*)(Kbase + (size_t)row1 * HD + ch1);
    s16x8 rV0 = *(const s16x8*)(Vbase + (size_t)row0 * N_DIM + ch0);
    s16x8 rV1 = *(const s16x8*)(Vbase + (size_t)row1 * N_DIM + ch1);

    for (int kt = 0; kt < 16; ++kt) {
        __builtin_amdgcn_s_barrier();

        *(s16x8*)&sK[row0][ch0] = rK0;
        *(s16x8*)&sK[row1][ch1] = rK1;
        *(s16x8*)&sV[row0][ch0] = rV0;
        *(s16x8*)&sV[row1][ch1] = rV1;

        if (kt < 15) {
            rK0 = *(const s16x8*)(Kbase + (size_t)((kt + 1) * 64 + row0) * HD + ch0);
            rK1 = *(const s16x8*)(Kbase + (size_t)((kt + 1) * 64 + row1) * HD + ch1);
            rV0 = *(const s16x8*)(Vbase + (size_t)row0 * N_DIM + (kt + 1) * 64 + ch0);
            rV1 = *(const s16x8*)(Vbase + (size_t)row1 * N_DIM + (kt + 1) * 64 + ch1);
        }

        asm volatile("s_waitcnt lgkmcnt(0)" ::: "memory");
        __builtin_amdgcn_sched_barrier(0);
        __builtin_amdgcn_s_barrier();
        __builtin_amdgcn_sched_barrier(0);

        f32x4 sA[4] = {}, sB[4] = {};
        __builtin_amdgcn_s_setprio(1);
        #pragma unroll
        for (int st = 0; st < 4; ++st) {
            f16x8 a0 = *(const f16x8*)&sK[16 * st + c][8 * g];
            f16x8 a1 = *(const f16x8*)&sK[16 * st + c][32 + 8 * g];
            sA[st] = __builtin_amdgcn_mfma_f32_16x16x32_f16(a0, qA0, sA[st], 0, 0, 0);
            sA[st] = __builtin_amdgcn_mfma_f32_16x16x32_f16(a1, qA1, sA[st], 0, 0, 0);
            sB[st] = __builtin_amdgcn_mfma_f32_16x16x32_f16(a0, qB0, sB[st], 0, 0, 0);
            sB[st] = __builtin_amdgcn_mfma_f32_16x16x32_f16(a1, qB1, sB[st], 0, 0, 0);
        }
        __builtin_amdgcn_s_setprio(0);

        #pragma unroll
        for (int st = 0; st < 4; ++st) {
            float pA[4], pB[4];
            #pragma unroll
            for (int r = 0; r < 4; ++r) {
                pA[r] = __builtin_amdgcn_exp2f(sA[st][r]);
                pB[r] = __builtin_amdgcn_exp2f(sB[st][r]);
            }
            __half2 a01 = __float22half2_rn(make_float2(pA[0], pA[1]));
            __half2 a23 = __float22half2_rn(make_float2(pA[2], pA[3]));
            __half2 b01 = __float22half2_rn(make_float2(pB[0], pB[1]));
            __half2 b23 = __float22half2_rn(make_float2(pB[2], pB[3]));
            *(uint2*)&sP[wv][0][c][16 * st + 4 * g] =
                make_uint2(*(unsigned*)&a01, *(unsigned*)&a23);
            *(uint2*)&sP[wv][1][c][16 * st + 4 * g] =
                make_uint2(*(unsigned*)&b01, *(unsigned*)&b23);
        }

        __builtin_amdgcn_s_setprio(1);
        #pragma unroll
        for (int m = 0; m < 2; ++m) {
            f16x8 pbA = *(const f16x8*)&sP[wv][0][c][32 * m + 8 * g];
            f16x8 pbB = *(const f16x8*)&sP[wv][1][c][32 * m + 8 * g];
            #pragma unroll
            for (int sd = 0; sd < 4; ++sd) {
                f16x8 va = *(const f16x8*)&sV[16 * sd + c][32 * m + 8 * g];
                accA[sd] = __builtin_amdgcn_mfma_f32_16x16x32_f16(va, pbA, accA[sd], 0, 0, 0);
                accB[sd] = __builtin_amdgcn_mfma_f32_16x16x32_f16(va, pbB, accB[sd], 0, 0, 0);
            }
            lAcc[0] = __builtin_amdgcn_mfma_f32_16x16x32_f16(ones, pbA, lAcc[0], 0, 0, 0);
            lAcc[1] = __builtin_amdgcn_mfma_f32_16x16x32_f16(ones, pbB, lAcc[1], 0, 0, 0);
        }
        __builtin_amdgcn_s_setprio(0);
    }

    float invA = 1.0f / lAcc[0][0];
    float invB = 1.0f / lAcc[1][0];

    const int b = bh / H_DIM, h = bh % H_DIM;
    #pragma unroll
    for (int sub = 0; sub < 2; ++sub) {
        const f32x4* acc = sub ? accB : accA;
        float invl = sub ? invB : invA;
        const int q = q0 + wv * 32 + sub * 16 + c;
        const int m  = b * N_DIM + q;
        const int p_ = m >> 7, mr = m & 127;
        #pragma unroll
        for (int sd = 0; sd < 4; ++sd) {
            int kdim = h * 64 + 16 * sd + 4 * g;
            int kb = kdim >> 5;
            int gg = (kdim >> 3) & 3;
            int e  = kdim & 7;               // 0 or 4
            size_t a = ((((size_t)p_ * 24 + kb) * 4 + gg) * 128 + mr) * 8 + e;
            unsigned short hs[4];
            #pragma unroll
            for (int r = 0; r < 4; ++r)
                hs[r] = f2h(acc[sd][r] * invl);
            *(uint2*)(Xb + a) =
                make_uint2((unsigned)hs[0] | ((unsigned)hs[1] << 16),
                           (unsigned)hs[2] | ((unsigned)hs[3] << 16));
        }
    }
}

// ---------------------------------------------------------------------------
extern "C" void kernel_launch(void* const* d_in, const int* in_sizes, int n_in,
                              void* d_out, int out_size, void* d_ws, size_t ws_size,
                              hipStream_t stream)
{
    const float* query = (const float*)d_in[0];
    const float* key_  = (const float*)d_in[1];
    const float* value = (const float*)d_in[2];
    const int*   qpos  = (const int*)d_in[3];
    const int*   kpos  = (const int*)d_in[4];
    const float* Wq    = (const float*)d_in[5];
    const float* Wk    = (const float*)d_in[6];
    const float* Wv    = (const float*)d_in[7];
    const float* Wo    = (const float*)d_in[8];
    const float* bo    = (const float*)d_in[9];
    float* out = (float*)d_out;

    unsigned short* XS  = (unsigned short*)d_ws;     // 3 x TEN (pk fp16 q,k,v)
    unsigned short* WS  = XS + 3 * TEN;              // 4 x WN  (pk fp16 Wq..Wo)
    unsigned short* Qh  = WS + 4 * WN;               // fp16 head layout
    unsigned short* Kh  = Qh + TEN;
    unsigned short* Vt  = Kh + TEN;                  // fp16 (B,H,64,N)
    unsigned short* Xb  = Vt + TEN;                  // fp16 (pk)
    float2* tab = (float2*)(Xb + TEN);               // 512 float2

    convAll<<<dim3(24, 64, 4), 256, 0, stream>>>(
        query, key_, value, Wq, Wk, Wv, Wo, XS, WS, tab);

    gemmF<1><<<dim3(1152), 256, 33792, stream>>>(
        XS + 0 * TEN, XS + 1 * TEN, XS + 2 * TEN,
        WS + 0 * WN, WS + 1 * WN, WS + 2 * WN,
        qpos, kpos, tab, Qh, Kh, Vt, nullptr, nullptr);

    attn_f16<<<dim3(768), 256, 0, stream>>>(Qh, Kh, Vt, Xb);

    gemmF<0><<<dim3(768), 256, 24576, stream>>>(
        Xb, nullptr, nullptr,
        WS + 3 * WN, nullptr, nullptr,
        nullptr, nullptr, nullptr, nullptr, nullptr, nullptr, bo, out);
}